// Round 1
// baseline (449.154 us; speedup 1.0000x reference)
//
#include <hip/hip_runtime.h>

typedef unsigned short u16;
typedef float f4v __attribute__((ext_vector_type(4)));
typedef short s8v __attribute__((ext_vector_type(8)));

#define SCALE_ 0.08838834764831845f

__device__ __forceinline__ u16 f2b(float f) {
    union { float f; unsigned u; } c; c.f = f;
    unsigned u = c.u + 0x7fffu + ((c.u >> 16) & 1u);
    return (u16)(u >> 16);
}

// ---------------------------------------------------------------------------
// GEMM: C[m][n] = sum_k A[m][k] * B[n][k]   (B^T layout, both row-major, K-contig)
// A: fp32 (ABF16=0) or bf16 (ABF16=1); B: fp32 weights; C: fp32.
// Tile 64x128, BK=64, 4 waves; reg-prefetch next K-tile during compute.
// ---------------------------------------------------------------------------
template <int ABF16>
__global__ __launch_bounds__(256) void fgemm_bt(const void* __restrict__ Ap,
                                                const float* __restrict__ Bp,
                                                float* __restrict__ Cp,
                                                int M, int N, int K) {
    __shared__ __align__(16) char At[64 * 128];    // 64 rows * 64 bf16
    __shared__ __align__(16) char Bt[128 * 128];   // 128 rows * 64 bf16
    const int tid = threadIdx.x, lane = tid & 63, wid = tid >> 6;
    const int lm = lane & 15, lg = lane >> 4;
    const int m0 = blockIdx.y * 64, n0 = blockIdx.x * 128;
    const int NT = K >> 6;

    f4v acc[4][2];
#pragma unroll
    for (int mi = 0; mi < 4; mi++)
#pragma unroll
        for (int ni = 0; ni < 2; ni++) acc[mi][ni] = (f4v){0.f, 0.f, 0.f, 0.f};

    float fA[2][8];
    s8v   hA[2];
    float fB[4][8];

    auto loadT = [&](int kt) {
#pragma unroll
        for (int i = 0; i < 2; i++) {
            int c = tid + i * 256; int r = c >> 3, k8 = c & 7;
            if constexpr (ABF16) {
                hA[i] = *(const s8v*)((const u16*)Ap + (size_t)(m0 + r) * K + kt * 64 + k8 * 8);
            } else {
                const float* p = (const float*)Ap + (size_t)(m0 + r) * K + kt * 64 + k8 * 8;
                float4 u = *(const float4*)p, v = *(const float4*)(p + 4);
                fA[i][0] = u.x; fA[i][1] = u.y; fA[i][2] = u.z; fA[i][3] = u.w;
                fA[i][4] = v.x; fA[i][5] = v.y; fA[i][6] = v.z; fA[i][7] = v.w;
            }
        }
#pragma unroll
        for (int i = 0; i < 4; i++) {
            int c = tid + i * 256; int r = c >> 3, k8 = c & 7;
            const float* p = Bp + (size_t)(n0 + r) * K + kt * 64 + k8 * 8;
            float4 u = *(const float4*)p, v = *(const float4*)(p + 4);
            fB[i][0] = u.x; fB[i][1] = u.y; fB[i][2] = u.z; fB[i][3] = u.w;
            fB[i][4] = v.x; fB[i][5] = v.y; fB[i][6] = v.z; fB[i][7] = v.w;
        }
    };

    auto storeLDS = [&]() {
#pragma unroll
        for (int i = 0; i < 2; i++) {
            int c = tid + i * 256; int r = c >> 3, k8 = c & 7;
            s8v hv;
            if constexpr (ABF16) hv = hA[i];
            else {
#pragma unroll
                for (int j = 0; j < 8; j++) hv[j] = (short)f2b(fA[i][j]);
            }
            *(s8v*)(At + ((r * 128 + k8 * 16) ^ ((r & 7) << 4))) = hv;
        }
#pragma unroll
        for (int i = 0; i < 4; i++) {
            int c = tid + i * 256; int r = c >> 3, k8 = c & 7;
            s8v hv;
#pragma unroll
            for (int j = 0; j < 8; j++) hv[j] = (short)f2b(fB[i][j]);
            *(s8v*)(Bt + ((r * 128 + k8 * 16) ^ ((r & 7) << 4))) = hv;
        }
    };

    loadT(0);
    for (int kt = 0; kt < NT; ++kt) {
        __syncthreads();
        storeLDS();
        __syncthreads();
        if (kt + 1 < NT) loadT(kt + 1);
#pragma unroll
        for (int ks = 0; ks < 2; ks++) {
            s8v av[4], bv[2];
#pragma unroll
            for (int mi = 0; mi < 4; mi++) {
                int r = mi * 16 + lm;
                av[mi] = *(const s8v*)(At + ((r * 128 + ks * 64 + lg * 16) ^ ((r & 7) << 4)));
            }
#pragma unroll
            for (int ni = 0; ni < 2; ni++) {
                int r = wid * 32 + ni * 16 + lm;
                bv[ni] = *(const s8v*)(Bt + ((r * 128 + ks * 64 + lg * 16) ^ ((r & 7) << 4)));
            }
#pragma unroll
            for (int mi = 0; mi < 4; mi++)
#pragma unroll
                for (int ni = 0; ni < 2; ni++)
                    acc[mi][ni] = __builtin_amdgcn_mfma_f32_16x16x32_bf16(av[mi], bv[ni], acc[mi][ni], 0, 0, 0);
        }
    }

#pragma unroll
    for (int mi = 0; mi < 4; mi++)
#pragma unroll
        for (int ni = 0; ni < 2; ni++)
#pragma unroll
            for (int r = 0; r < 4; r++) {
                int m = m0 + mi * 16 + lg * 4 + r;
                int n = n0 + wid * 32 + ni * 16 + lm;
                Cp[(size_t)m * N + n] = acc[mi][ni][r];
            }
}

// ---------------------------------------------------------------------------
// Fused RMSNorm + RoPE + scale + bf16 convert. One wave per (b,s,h) row of 128.
// ---------------------------------------------------------------------------
__global__ __launch_bounds__(256) void nrope_k(const float* __restrict__ src,
                                               u16* __restrict__ dst,
                                               const float* __restrict__ w,
                                               const int* __restrict__ cseq,
                                               int nheads, float oscale) {
    const int lane = threadIdx.x & 63;
    const int rid = blockIdx.x * 4 + (threadIdx.x >> 6);
    const int s = (rid / nheads) & 127;
    const int b = rid / (nheads * 128);
    const float* p = src + (size_t)rid * 128;
    float x1 = p[lane], x2 = p[lane + 64];
    float ss = x1 * x1 + x2 * x2;
#pragma unroll
    for (int off = 1; off < 64; off <<= 1) ss += __shfl_xor(ss, off);
    float inv = rsqrtf(ss * (1.0f / 128.0f) + 1e-6f);
    float n1 = x1 * inv * w[lane];
    float n2 = x2 * inv * w[lane + 64];
    float pos = (float)(cseq[b] + s);
    float ang = pos * powf(10000.0f, -(float)lane * (1.0f / 64.0f));
    float cs = cosf(ang), sn = sinf(ang);
    dst[(size_t)rid * 128 + lane]      = f2b((n1 * cs - n2 * sn) * oscale);
    dst[(size_t)rid * 128 + lane + 64] = f2b((n2 * cs + n1 * sn) * oscale);
}

__global__ __launch_bounds__(256) void cvt_bf16k(const float* __restrict__ s,
                                                 u16* __restrict__ d, int n4) {
    int i = blockIdx.x * blockDim.x + threadIdx.x;
    if (i < n4) {
        float4 f = ((const float4*)s)[i];
        ushort4 o;
        o.x = f2b(f.x); o.y = f2b(f.y); o.z = f2b(f.z); o.w = f2b(f.w);
        ((ushort4*)d)[i] = o;
    }
}

// ---------------------------------------------------------------------------
// Flash attention. Block = (b, h, q-half64). 4 waves x 16 q-rows. KV tile = 64.
// Q frags in regs; K staged fp32->bf16 in swizzled LDS; V B-frags direct from
// global (coalesced 64B segments); P via per-wave swizzled LDS round-trip.
// ---------------------------------------------------------------------------
__global__ __launch_bounds__(256) void fattn_k(const u16* __restrict__ qb,
                                               const u16* __restrict__ kb,
                                               const u16* __restrict__ vb,
                                               const float* __restrict__ kc,
                                               const float* __restrict__ vc,
                                               const int* __restrict__ btab,
                                               const int* __restrict__ cseq,
                                               u16* __restrict__ ob) {
    __shared__ __align__(16) char Ks[64 * 256];    // 64 rows * 128 bf16, swizzled
    __shared__ __align__(16) char Ps[4][2048];     // per wave: 16 rows * 64 bf16

    const int tid = threadIdx.x, lane = tid & 63, wid = tid >> 6;
    const int lm = lane & 15, lg = lane >> 4;
    const int bid = blockIdx.x;
    const int half = bid & 1, h = (bid >> 1) & 31, b = bid >> 6;
    const int hk = h >> 2;

    // persistent Q A-fragments (scale already folded in)
    s8v qa[4];
    {
        const u16* qp = qb + ((size_t)((b * 128 + half * 64 + wid * 16 + lm) * 32 + h)) * 128 + lg * 8;
#pragma unroll
        for (int ks = 0; ks < 4; ks++) qa[ks] = *(const s8v*)(qp + ks * 32);
    }

    float m_run[4], l_run[4];
    f4v acc[8];
#pragma unroll
    for (int r = 0; r < 4; r++) { m_run[r] = -1e30f; l_run[r] = 0.f; }
#pragma unroll
    for (int dt = 0; dt < 8; dt++) acc[dt] = (f4v){0.f, 0.f, 0.f, 0.f};

    const int cl = cseq[b];
    const int ntc = (cl + 63) >> 6;       // cache tiles (skip fully-masked)
    const int ntot = ntc + 2;             // + two new-token tiles

    for (int it = 0; it < ntot; ++it) {
        const bool isnew = (it >= ntc);
        const int t0 = isnew ? (4096 + (it - ntc) * 64) : it * 64;
        __syncthreads();
        // ---- stage K tile ----
        if (!isnew) {
#pragma unroll
            for (int i = 0; i < 4; i++) {
                int c = tid + i * 256; int r = c >> 4, d8 = c & 15;
                int p = t0 + r;
                int page = btab[b * 16 + (p >> 8)];
                const float* src = kc + (((size_t)page * 256 + (p & 255)) * 8 + hk) * 128 + d8 * 8;
                float4 f0 = *(const float4*)src;
                float4 f1 = *(const float4*)(src + 4);
                s8v v;
                v[0] = (short)f2b(f0.x); v[1] = (short)f2b(f0.y);
                v[2] = (short)f2b(f0.z); v[3] = (short)f2b(f0.w);
                v[4] = (short)f2b(f1.x); v[5] = (short)f2b(f1.y);
                v[6] = (short)f2b(f1.z); v[7] = (short)f2b(f1.w);
                *(s8v*)(Ks + ((r * 256 + d8 * 16) ^ ((r & 7) << 4))) = v;
            }
        } else {
#pragma unroll
            for (int i = 0; i < 4; i++) {
                int c = tid + i * 256; int r = c >> 4, d8 = c & 15;
                int s = (t0 - 4096) + r;
                const u16* src = kb + (((size_t)(b * 128 + s) * 8 + hk)) * 128 + d8 * 8;
                s8v v = *(const s8v*)src;
                *(s8v*)(Ks + ((r * 256 + d8 * 16) ^ ((r & 7) << 4))) = v;
            }
        }
        __syncthreads();

        // ---- Q @ K^T : 4 col-tiles of 16, K-dim 128 = 4 chained MFMAs ----
        f4v sc[4];
#pragma unroll
        for (int ct = 0; ct < 4; ct++) sc[ct] = (f4v){0.f, 0.f, 0.f, 0.f};
#pragma unroll
        for (int ct = 0; ct < 4; ct++) {
#pragma unroll
            for (int ks = 0; ks < 4; ks++) {
                int r = ct * 16 + lm;
                s8v kf = *(const s8v*)(Ks + ((r * 256 + ks * 64 + lg * 16) ^ ((r & 7) << 4)));
                sc[ct] = __builtin_amdgcn_mfma_f32_16x16x32_bf16(qa[ks], kf, sc[ct], 0, 0, 0);
            }
        }
        // mask partial cache tile
        if (!isnew && (t0 + 64 > cl)) {
#pragma unroll
            for (int ct = 0; ct < 4; ct++) {
                int p = t0 + ct * 16 + lm;
                if (p >= cl) { sc[ct][0] = -1e30f; sc[ct][1] = -1e30f; sc[ct][2] = -1e30f; sc[ct][3] = -1e30f; }
            }
        }

        // ---- online softmax (rows live in 16-lane groups) ----
        float mnew[4], corr[4], rsum[4];
#pragma unroll
        for (int r = 0; r < 4; r++) {
            float mt = fmaxf(fmaxf(sc[0][r], sc[1][r]), fmaxf(sc[2][r], sc[3][r]));
#pragma unroll
            for (int off = 1; off < 16; off <<= 1) mt = fmaxf(mt, __shfl_xor(mt, off));
            float mn = fmaxf(m_run[r], mt);
            corr[r] = __expf(m_run[r] - mn);
            m_run[r] = mn;
            mnew[r] = mn;
            rsum[r] = 0.f;
        }
#pragma unroll
        for (int ct = 0; ct < 4; ct++) {
#pragma unroll
            for (int r = 0; r < 4; r++) {
                float pv = __expf(sc[ct][r] - mnew[r]);
                rsum[r] += pv;
                int row = lg * 4 + r;
                *(u16*)(Ps[wid] + ((row * 128 + (ct * 16 + lm) * 2) ^ ((row & 7) << 4))) = f2b(pv);
            }
        }
#pragma unroll
        for (int r = 0; r < 4; r++) {
            float rs = rsum[r];
#pragma unroll
            for (int off = 1; off < 16; off <<= 1) rs += __shfl_xor(rs, off);
            l_run[r] = l_run[r] * corr[r] + rs;
        }
#pragma unroll
        for (int dt = 0; dt < 8; dt++) {
#pragma unroll
            for (int r = 0; r < 4; r++) acc[dt][r] *= corr[r];
        }

        // ---- P A-frags from per-wave LDS ----
        s8v pa[2];
#pragma unroll
        for (int k2 = 0; k2 < 2; k2++)
            pa[k2] = *(const s8v*)(Ps[wid] + ((lm * 128 + k2 * 64 + lg * 16) ^ ((lm & 7) << 4)));

        // ---- P @ V : V B-frags directly from global ----
        if (!isnew) {
#pragma unroll
            for (int k2 = 0; k2 < 2; k2++) {
                int prow = t0 + k2 * 32 + lg * 8;       // 8-row run stays in one page
                int page = btab[b * 16 + (prow >> 8)];
                const float* vsrc = vc + (((size_t)page * 256 + (prow & 255)) * 8 + hk) * 128 + lm;
#pragma unroll
                for (int dt = 0; dt < 8; dt++) {
                    const float* vp = vsrc + dt * 16;
                    s8v bf;
#pragma unroll
                    for (int j = 0; j < 8; j++) bf[j] = (short)f2b(vp[(size_t)j * 1024]);
                    acc[dt] = __builtin_amdgcn_mfma_f32_16x16x32_bf16(pa[k2], bf, acc[dt], 0, 0, 0);
                }
            }
        } else {
            int s0 = t0 - 4096;
#pragma unroll
            for (int k2 = 0; k2 < 2; k2++) {
                const u16* vsrc = vb + ((size_t)(b * 128 + s0 + k2 * 32 + lg * 8) * 8 + hk) * 128 + lm;
#pragma unroll
                for (int dt = 0; dt < 8; dt++) {
                    s8v bf;
#pragma unroll
                    for (int j = 0; j < 8; j++) bf[j] = (short)vsrc[dt * 16 + (size_t)j * 1024];
                    acc[dt] = __builtin_amdgcn_mfma_f32_16x16x32_bf16(pa[k2], bf, acc[dt], 0, 0, 0);
                }
            }
        }
    }

    // ---- epilogue: o = acc / l ----
#pragma unroll
    for (int dt = 0; dt < 8; dt++) {
#pragma unroll
        for (int r = 0; r < 4; r++) {
            int s = half * 64 + wid * 16 + lg * 4 + r;
            float o = acc[dt][r] / l_run[r];
            ob[((size_t)(b * 128 + s) * 32 + h) * 128 + dt * 16 + lm] = f2b(o);
        }
    }
}

// ---------------------------------------------------------------------------
extern "C" void kernel_launch(void* const* d_in, const int* in_sizes, int n_in,
                              void* d_out, int out_size, void* d_ws, size_t ws_size,
                              hipStream_t stream) {
    const float* x   = (const float*)d_in[0];
    const float* Wq  = (const float*)d_in[1];
    const float* Wk  = (const float*)d_in[2];
    const float* Wv  = (const float*)d_in[3];
    const float* Wo  = (const float*)d_in[4];
    const float* qnw = (const float*)d_in[5];
    const float* knw = (const float*)d_in[6];
    const float* kc  = (const float*)d_in[7];
    const float* vc  = (const float*)d_in[8];
    const int* btab  = (const int*)d_in[9];
    const int* cseq  = (const int*)d_in[10];
    float* out = (float*)d_out;

    char* ws = (char*)d_ws;
    float* qf = (float*)(ws + 0);              // 512x4096 f32  (8 MB)
    float* kf = (float*)(ws + 8388608);        // 512x1024 f32  (2 MB)
    float* vf = (float*)(ws + 10485760);       // 512x1024 f32  (2 MB)
    u16*   qb = (u16*)(ws + 12582912);         // 512x4096 bf16 (4 MB)
    u16*   kb = (u16*)(ws + 16777216);         // 512x1024 bf16 (1 MB)
    u16*   vb = (u16*)(ws + 17825792);         // 512x1024 bf16 (1 MB)
    u16*   ob = (u16*)(ws + 18874368);         // 512x4096 bf16 (4 MB)

    dim3 blk(256, 1, 1);
    fgemm_bt<0><<<dim3(32, 8, 1), blk, 0, stream>>>(x, Wq, qf, 512, 4096, 4096);
    fgemm_bt<0><<<dim3(8, 8, 1),  blk, 0, stream>>>(x, Wk, kf, 512, 1024, 4096);
    fgemm_bt<0><<<dim3(8, 8, 1),  blk, 0, stream>>>(x, Wv, vf, 512, 1024, 4096);
    nrope_k<<<dim3(4096, 1, 1), blk, 0, stream>>>(qf, qb, qnw, cseq, 32, SCALE_);
    nrope_k<<<dim3(1024, 1, 1), blk, 0, stream>>>(kf, kb, knw, cseq, 8, 1.0f);
    cvt_bf16k<<<dim3(512, 1, 1), blk, 0, stream>>>(vf, vb, 131072);
    fattn_k<<<dim3(256, 1, 1), blk, 0, stream>>>(qb, kb, vb, kc, vc, btab, cseq, ob);
    fgemm_bt<1><<<dim3(32, 8, 1), blk, 0, stream>>>(ob, Wo, out, 512, 4096, 4096);
}